// Round 1
// baseline (180.008 us; speedup 1.0000x reference)
//
#include <hip/hip_runtime.h>

// Problem constants (from reference): B=8, E=512, L=4096, D=256, all fp32.
#define B_N 8
#define E_N 512
#define L_N 4096
#define D_N 256

typedef __attribute__((ext_vector_type(8))) short short8;   // 8 bf16 = 4 VGPRs (MFMA A/B frag)
typedef __attribute__((ext_vector_type(4))) short short4v;  // 4 bf16 = 8B LDS store
typedef __attribute__((ext_vector_type(4))) float f32x4;    // MFMA acc / global float4

// round-to-nearest-even fp32 -> bf16 bits
__device__ __forceinline__ unsigned short f2bf(float f) {
    unsigned u = __float_as_uint(f);
    u += 0x7fffu + ((u >> 16) & 1u);
    return (unsigned short)(u >> 16);
}

// LDS leading dim: 64 data + 8 pad -> 144B row stride (16B aligned for b128 frag
// reads; spreads banks: frag reads conflict-free, A-writes conflict-free,
// B transpose-writes ~8-way (accepted this round)).
#define LDT 72

__global__ __launch_bounds__(256)
void mp_gemm(const float* __restrict__ doc,   // [B, L, D]
             const float* __restrict__ map,   // [B, E, L]
             const float* __restrict__ lens,  // [B, E]
             float* __restrict__ out)         // [B, E, D]
{
    __shared__ unsigned short As[64 * LDT];   // As[m][k] : map tile, K-contig
    __shared__ unsigned short Bs[64 * LDT];   // Bs[n][k] : doc tile transposed, K-contig
    __shared__ float invLen[64];

    const int b  = blockIdx.y;
    const int e0 = (blockIdx.x >> 2) * 64;    // E tile (8 tiles)
    const int d0 = (blockIdx.x & 3) * 64;     // D tile (4 tiles)

    const float* docB = doc + (size_t)b * L_N * D_N;
    const float* mapB = map + (size_t)b * E_N * L_N;
    float*       outB = out + (size_t)b * E_N * D_N;

    const int tid  = threadIdx.x;
    const int lane = tid & 63;
    const int wave = tid >> 6;

    if (tid < 64) invLen[tid] = 1.0f / lens[(size_t)b * E_N + e0 + tid];

    // ---- staging assignments ----
    // A tile 64(m) x 64(k) fp32: 1024 float4; thread t handles rows (t>>4)+16r, col4 = t&15
    const int aRow0 = tid >> 4;
    const int aCol4 = tid & 15;
    // B tile 64(k) x 64(n) fp32: each thread owns one 4x4 micro-block, transposes in regs
    const int nb = tid & 15;   // n block (coalesced global reads)
    const int kb = tid >> 4;   // k block

    f32x4 ar[4], br[4];

    // prefetch tile 0
    {
        const int k0 = 0;
        #pragma unroll
        for (int r = 0; r < 4; ++r)
            ar[r] = *(const f32x4*)(mapB + (size_t)(e0 + aRow0 + r * 16) * L_N + k0 + aCol4 * 4);
        #pragma unroll
        for (int i = 0; i < 4; ++i)
            br[i] = *(const f32x4*)(docB + (size_t)(k0 + kb * 4 + i) * D_N + d0 + nb * 4);
    }

    // ---- compute setup ----
    const int wm = wave >> 1;       // wave's 32-row block within tile
    const int wn = wave & 1;        // wave's 32-col block
    const int fm = lane & 15;       // fragment row/col
    const int q  = lane >> 4;       // k-group (8 elems each)

    f32x4 acc[2][2] = {};

    for (int it = 0; it < 64; ++it) {
        if (it) __syncthreads();            // all waves done reading previous tile

        // regs -> LDS (with fp32->bf16 convert; B transposed 4x4)
        #pragma unroll
        for (int r = 0; r < 4; ++r) {
            short4v w;
            w[0] = (short)f2bf(ar[r][0]);
            w[1] = (short)f2bf(ar[r][1]);
            w[2] = (short)f2bf(ar[r][2]);
            w[3] = (short)f2bf(ar[r][3]);
            *(short4v*)&As[(aRow0 + r * 16) * LDT + aCol4 * 4] = w;
        }
        #pragma unroll
        for (int j = 0; j < 4; ++j) {
            short4v w;
            w[0] = (short)f2bf(br[0][j]);
            w[1] = (short)f2bf(br[1][j]);
            w[2] = (short)f2bf(br[2][j]);
            w[3] = (short)f2bf(br[3][j]);
            *(short4v*)&Bs[(nb * 4 + j) * LDT + kb * 4] = w;
        }
        __syncthreads();

        // prefetch next tile into regs (overlaps with MFMA below)
        if (it < 63) {
            const int k0 = (it + 1) * 64;
            #pragma unroll
            for (int r = 0; r < 4; ++r)
                ar[r] = *(const f32x4*)(mapB + (size_t)(e0 + aRow0 + r * 16) * L_N + k0 + aCol4 * 4);
            #pragma unroll
            for (int i = 0; i < 4; ++i)
                br[i] = *(const f32x4*)(docB + (size_t)(k0 + kb * 4 + i) * D_N + d0 + nb * 4);
        }

        // compute on the staged 64x64x64 tile: 2 K-steps of 32
        #pragma unroll
        for (int kk = 0; kk < 2; ++kk) {
            short8 af[2], bf[2];
            #pragma unroll
            for (int mi = 0; mi < 2; ++mi) {
                const unsigned short* p = &As[(wm * 32 + mi * 16 + fm) * LDT + kk * 32 + q * 8];
                af[mi] = *(const short8*)p;   // 16B aligned (LDT=72)
            }
            #pragma unroll
            for (int ni = 0; ni < 2; ++ni) {
                const unsigned short* p = &Bs[(wn * 32 + ni * 16 + fm) * LDT + kk * 32 + q * 8];
                bf[ni] = *(const short8*)p;
            }
            #pragma unroll
            for (int mi = 0; mi < 2; ++mi)
                #pragma unroll
                for (int ni = 0; ni < 2; ++ni)
                    acc[mi][ni] = __builtin_amdgcn_mfma_f32_16x16x32_bf16(
                        af[mi], bf[ni], acc[mi][ni], 0, 0, 0);
        }
    }

    // ---- epilogue: C/D layout col = lane&15, row = (lane>>4)*4 + i ----
    #pragma unroll
    for (int mi = 0; mi < 2; ++mi) {
        const int rLoc = wm * 32 + mi * 16 + q * 4;
        #pragma unroll
        for (int ni = 0; ni < 2; ++ni) {
            const int c = d0 + wn * 32 + ni * 16 + fm;
            #pragma unroll
            for (int i = 0; i < 4; ++i) {
                const int rr = rLoc + i;
                outB[(size_t)(e0 + rr) * D_N + c] = acc[mi][ni][i] * invLen[rr];
            }
        }
    }
}

extern "C" void kernel_launch(void* const* d_in, const int* in_sizes, int n_in,
                              void* d_out, int out_size, void* d_ws, size_t ws_size,
                              hipStream_t stream) {
    const float* doc  = (const float*)d_in[0];  // doc_state [B,L,D]
    const float* map  = (const float*)d_in[1];  // entity_mapping [B,E,L]
    const float* lens = (const float*)d_in[2];  // entity_lens [B,E]
    float* out = (float*)d_out;                 // [B,E,D] fp32

    dim3 grid(32, 8);   // (E/64)*(D/64)=8*4 tiles, B batches
    mp_gemm<<<grid, 256, 0, stream>>>(doc, map, lens, out);
}

// Round 2
// 154.224 us; speedup vs baseline: 1.1672x; 1.1672x over previous
//
#include <hip/hip_runtime.h>

// Problem constants (from reference): B=8, E=512, L=4096, D=256, all fp32.
#define B_N 8
#define E_N 512
#define L_N 4096
#define D_N 256

#define SPLITK 4              // K-chunks -> 1024 blocks -> 4 blocks/CU
#define KC_LEN (L_N / SPLITK) // 1024
#define KC_ITERS (KC_LEN / 64)

typedef __attribute__((ext_vector_type(8))) short short8;   // 8 bf16 = 4 VGPRs (MFMA A/B frag)
typedef __attribute__((ext_vector_type(4))) short short4v;  // 4 bf16 = 8B LDS store
typedef __attribute__((ext_vector_type(4))) float f32x4;    // MFMA acc / global float4

// round-to-nearest-even fp32 -> bf16 bits
__device__ __forceinline__ unsigned short f2bf(float f) {
    unsigned u = __float_as_uint(f);
    u += 0x7fffu + ((u >> 16) & 1u);
    return (unsigned short)(u >> 16);
}

// LDS leading dim: 64 data + 8 pad (16B-aligned b128 frag reads).
#define LDT 72

__global__ __launch_bounds__(256)
void mp_gemm(const float* __restrict__ doc,   // [B, L, D]
             const float* __restrict__ map,   // [B, E, L]
             const float* __restrict__ lens,  // [B, E]
             float* __restrict__ out)         // [B, E, D] (pre-zeroed; atomic accumulate)
{
    __shared__ unsigned short As[64 * LDT];   // As[m][k] : map tile, K-contig
    __shared__ unsigned short Bs[64 * LDT];   // Bs[n][k] : doc tile transposed, K-contig
    __shared__ float invLen[64];

    const int b  = blockIdx.y;
    const int e0 = (blockIdx.x >> 2) * 64;    // E tile (8 tiles)
    const int d0 = (blockIdx.x & 3) * 64;     // D tile (4 tiles)
    const int kc0 = blockIdx.z * KC_LEN;      // split-K chunk base

    const float* docB = doc + (size_t)b * L_N * D_N;
    const float* mapB = map + (size_t)b * E_N * L_N;
    float*       outB = out + (size_t)b * E_N * D_N;

    const int tid  = threadIdx.x;
    const int lane = tid & 63;
    const int wave = tid >> 6;

    if (tid < 64) invLen[tid] = 1.0f / lens[(size_t)b * E_N + e0 + tid];

    // ---- staging assignments ----
    // A tile 64(m) x 64(k) fp32: thread t handles rows (t>>4)+16r, col4 = t&15
    const int aRow0 = tid >> 4;
    const int aCol4 = tid & 15;
    // B tile 64(k) x 64(n) fp32: each thread owns one 4x4 micro-block, transposes in regs
    const int nb = tid & 15;   // n block (coalesced global reads)
    const int kb = tid >> 4;   // k block

    f32x4 ar[4], br[4];

    // prefetch tile 0
    {
        const int k0 = kc0;
        #pragma unroll
        for (int r = 0; r < 4; ++r)
            ar[r] = *(const f32x4*)(mapB + (size_t)(e0 + aRow0 + r * 16) * L_N + k0 + aCol4 * 4);
        #pragma unroll
        for (int i = 0; i < 4; ++i)
            br[i] = *(const f32x4*)(docB + (size_t)(k0 + kb * 4 + i) * D_N + d0 + nb * 4);
    }

    // ---- compute setup ----
    const int wm = wave >> 1;       // wave's 32-row block within tile
    const int wn = wave & 1;        // wave's 32-col block
    const int fm = lane & 15;       // fragment row/col
    const int q  = lane >> 4;       // k-group (8 elems each)

    f32x4 acc[2][2] = {};

    for (int it = 0; it < KC_ITERS; ++it) {
        if (it) __syncthreads();            // all waves done reading previous tile

        // regs -> LDS (with fp32->bf16 convert; B transposed 4x4)
        #pragma unroll
        for (int r = 0; r < 4; ++r) {
            short4v w;
            w[0] = (short)f2bf(ar[r][0]);
            w[1] = (short)f2bf(ar[r][1]);
            w[2] = (short)f2bf(ar[r][2]);
            w[3] = (short)f2bf(ar[r][3]);
            *(short4v*)&As[(aRow0 + r * 16) * LDT + aCol4 * 4] = w;
        }
        #pragma unroll
        for (int j = 0; j < 4; ++j) {
            short4v w;
            w[0] = (short)f2bf(br[0][j]);
            w[1] = (short)f2bf(br[1][j]);
            w[2] = (short)f2bf(br[2][j]);
            w[3] = (short)f2bf(br[3][j]);
            *(short4v*)&Bs[(nb * 4 + j) * LDT + kb * 4] = w;
        }
        __syncthreads();

        // prefetch next tile into regs (overlaps with MFMA below)
        if (it < KC_ITERS - 1) {
            const int k0 = kc0 + (it + 1) * 64;
            #pragma unroll
            for (int r = 0; r < 4; ++r)
                ar[r] = *(const f32x4*)(mapB + (size_t)(e0 + aRow0 + r * 16) * L_N + k0 + aCol4 * 4);
            #pragma unroll
            for (int i = 0; i < 4; ++i)
                br[i] = *(const f32x4*)(docB + (size_t)(k0 + kb * 4 + i) * D_N + d0 + nb * 4);
        }

        // compute on the staged 64x64x64 tile: 2 K-steps of 32
        #pragma unroll
        for (int kk = 0; kk < 2; ++kk) {
            short8 af[2], bf[2];
            #pragma unroll
            for (int mi = 0; mi < 2; ++mi) {
                const unsigned short* p = &As[(wm * 32 + mi * 16 + fm) * LDT + kk * 32 + q * 8];
                af[mi] = *(const short8*)p;   // 16B aligned (LDT=72)
            }
            #pragma unroll
            for (int ni = 0; ni < 2; ++ni) {
                const unsigned short* p = &Bs[(wn * 32 + ni * 16 + fm) * LDT + kk * 32 + q * 8];
                bf[ni] = *(const short8*)p;
            }
            #pragma unroll
            for (int mi = 0; mi < 2; ++mi)
                #pragma unroll
                for (int ni = 0; ni < 2; ++ni)
                    acc[mi][ni] = __builtin_amdgcn_mfma_f32_16x16x32_bf16(
                        af[mi], bf[ni], acc[mi][ni], 0, 0, 0);
        }
    }

    // ---- epilogue: scale partial by invLen (linear in split-K) and atomically accumulate.
    // C/D layout: col = lane&15, row = (lane>>4)*4 + i
    #pragma unroll
    for (int mi = 0; mi < 2; ++mi) {
        const int rLoc = wm * 32 + mi * 16 + q * 4;
        #pragma unroll
        for (int ni = 0; ni < 2; ++ni) {
            const int c = d0 + wn * 32 + ni * 16 + fm;
            #pragma unroll
            for (int i = 0; i < 4; ++i) {
                const int rr = rLoc + i;
                atomicAdd(&outB[(size_t)(e0 + rr) * D_N + c], acc[mi][ni][i] * invLen[rr]);
            }
        }
    }
}

extern "C" void kernel_launch(void* const* d_in, const int* in_sizes, int n_in,
                              void* d_out, int out_size, void* d_ws, size_t ws_size,
                              hipStream_t stream) {
    const float* doc  = (const float*)d_in[0];  // doc_state [B,L,D]
    const float* map  = (const float*)d_in[1];  // entity_mapping [B,E,L]
    const float* lens = (const float*)d_in[2];  // entity_lens [B,E]
    float* out = (float*)d_out;                 // [B,E,D] fp32

    // d_out is poisoned 0xAA before every call; split-K accumulates atomically.
    hipMemsetAsync(out, 0, (size_t)out_size * sizeof(float), stream);

    dim3 grid(32, 8, SPLITK);   // (E/64)*(D/64)=8*4 tiles, B batches, 4 K-chunks
    mp_gemm<<<grid, 256, 0, stream>>>(doc, map, lens, out);
}